// Round 1
// baseline (16793.289 us; speedup 1.0000x reference)
//
#include <hip/hip_runtime.h>
#include <math.h>

#define NB   32    // batch
#define TH   128   // scan steps
#define NL   6     // layers
#define DD   128   // model dim
#define NH   4     // heads
#define DHD  32    // head dim
#define TCAP 128   // max cached tokens
#define D3   384
#define D4   512

typedef _Float16 f16;
typedef _Float16 f16x8 __attribute__((ext_vector_type(8)));

// fp32 -> fp16 (RNE) weight conversion into workspace
__global__ void prep_kernel(const float* __restrict__ qkv, const float* __restrict__ proj,
                            const float* __restrict__ fc,  const float* __restrict__ fc2,
                            f16* __restrict__ out) {
    int i = blockIdx.x * blockDim.x + threadIdx.x;
    const int n0 = NL * DD * D3, n1 = NL * DD * DD, n2 = NL * DD * D4, n3 = NL * D4 * DD;
    const int total = n0 + n1 + n2 + n3;
    if (i >= total) return;
    float v;
    if (i < n0)                 v = qkv[i];
    else if (i < n0 + n1)       v = proj[i - n0];
    else if (i < n0 + n1 + n2)  v = fc[i - n0 - n1];
    else                        v = fc2[i - n0 - n1 - n2];
    out[i] = (f16)v;
}

__device__ __forceinline__ float wave_xor_sum(float v) {
    #pragma unroll
    for (int off = 1; off < 64; off <<= 1) v += __shfl_xor(v, off);
    return v;
}
__device__ __forceinline__ float wave_xor_max(float v) {
    #pragma unroll
    for (int off = 1; off < 64; off <<= 1) v = fmaxf(v, __shfl_xor(v, off));
    return v;
}
__device__ __forceinline__ float gelu_tanh(float v) {
    float t = v * v * v;
    return 0.5f * v * (1.f + tanhf(0.7978845608028654f * (v + 0.044715f * t)));
}

// One workgroup (512 threads) per batch element; 128 KV-cached decode steps.
// 5 barrier phases per layer (A:qkv+LN1, B:attn, C:proj, D:fc+LN2, E:fc2).
// Every weight/KV tile is prefetched into registers one phase ahead: the
// compiler's vmcnt(0) drain at each __syncthreads() completes the loads
// exactly when the next phase consumes them, hiding L2/HBM latency behind
// the previous phase's compute.
__global__ __launch_bounds__(512) void gpt_loop(
    const float* __restrict__ data,  const float* __restrict__ r,
    const float* __restrict__ wte_w, const float* __restrict__ wte_b,
    const float* __restrict__ wpe,
    const float* __restrict__ ln1_w, const float* __restrict__ ln1_b,
    const float* __restrict__ ln2_w, const float* __restrict__ ln2_b,
    const float* __restrict__ qkv_b, const float* __restrict__ proj_b,
    const float* __restrict__ fc_b,  const float* __restrict__ fc2_b,
    const float* __restrict__ lnf_w, const float* __restrict__ lnf_b,
    const float* __restrict__ head_w,const float* __restrict__ head_b,
    const f16* __restrict__ Wq, const f16* __restrict__ Wp,
    const f16* __restrict__ Wf, const f16* __restrict__ Wf2,
    f16* __restrict__ Kc, f16* __restrict__ Vc,
    float* __restrict__ Y)
{
    const int b    = blockIdx.x;
    const int tid  = threadIdx.x;
    const int lane = tid & 63;
    const int wid  = tid >> 6;

    __shared__ __align__(16) float x[DD], qv[DD], o[DD], hmid[D4];
    __shared__ __align__(16) float sc[NH][TCAP];
    __shared__ __align__(16) float c_ln1w[NL][DD], c_ln1b[NL][DD], c_ln2w[NL][DD], c_ln2b[NL][DD];
    __shared__ __align__(16) float c_qkvb[NL][D3], c_projb[NL][DD], c_fcb[NL][D4], c_fc2b[NL][DD];
    __shared__ __align__(16) float c_lnfw[DD], c_lnfb[DD], c_headw[DD], c_wte0[DD], c_wte1[DD], c_wteb[DD];

    const float p0 = data[b * 2 + 0];
    const float p1 = data[b * 2 + 1];
    const float hb = head_b[0];

    f16* Kb = Kc + (size_t)b * NL * TCAP * DD;
    f16* Vb = Vc + (size_t)b * NL * TCAP * DD;

    for (int idx = tid; idx < NL * DD; idx += 512) {
        int l = idx / DD, d = idx % DD;
        c_ln1w[l][d] = ln1_w[idx]; c_ln1b[l][d] = ln1_b[idx];
        c_ln2w[l][d] = ln2_w[idx]; c_ln2b[l][d] = ln2_b[idx];
        c_projb[l][d] = proj_b[idx]; c_fc2b[l][d] = fc2_b[idx];
    }
    for (int idx = tid; idx < NL * D3; idx += 512) c_qkvb[idx / D3][idx % D3] = qkv_b[idx];
    for (int idx = tid; idx < NL * D4; idx += 512) c_fcb[idx / D4][idx % D4] = fc_b[idx];
    if (tid < DD) {
        c_lnfw[tid] = lnf_w[tid]; c_lnfb[tid] = lnf_b[tid]; c_headw[tid] = head_w[tid];
        c_wte0[tid] = wte_w[tid]; c_wte1[tid] = wte_w[DD + tid]; c_wteb[tid] = wte_b[tid];
    }
    // zero-init this block's KV cache: rows > current step then contribute
    // exact 0 to AV, making full-width register prefetch safe.
    {
        float4 z4 = make_float4(0.f, 0.f, 0.f, 0.f);
        float4* K4 = (float4*)Kb; float4* V4 = (float4*)Vb;
        const int n4 = NL * TCAP * DD * 2 / 16;
        for (int idx = tid; idx < n4; idx += 512) { K4[idx] = z4; V4[idx] = z4; }
    }
    __syncthreads();

    // ---- prologue: state + x-init for step 0 + wq(layer 0) prefetch ----
    float s_reg = 0.f;                       // state lives in wave-0 registers
    if (wid == 0) {
        float e0 = r[b * TH + 0];            // s=0, u=0 at step 0
        x[lane]      = e0 * c_wte0[lane]      + c_wteb[lane]      + wpe[lane];
        x[lane + 64] = e0 * c_wte0[lane + 64] + c_wteb[lane + 64] + wpe[64 + lane];
    }

    const int cgq = lane & 7, ksq = lane >> 3;       // qkv/fc mapping: 8 cols x 8 k-splits
    const int cbq = wid * 64 + cgq * 8, k0q = ksq * 16;
    const int cg2 = lane & 1, ks2 = lane >> 1;       // proj/fc2 mapping
    const int cb2 = (wid * 2 + cg2) * 8;
    const int hh  = wid - 4;                          // head for waves 4..7
    const int vcg = lane & 3, vjs = lane >> 2;        // AV mapping: 4 col-groups x 16 j-splits

    f16x8 wq[16];
    if (wid < 6) {
        const f16* W = Wq + cbq;
        #pragma unroll
        for (int k = 0; k < 16; k++) wq[k] = *(const f16x8*)(W + (size_t)(k0q + k) * D3);
    }
    __syncthreads();

    for (int i = 0; i < TH; i++) {
        // step-top prefetches for the head/x-init phase (held in regs all step)
        const int inext = (i + 1 < TH) ? (i + 1) : (TH - 1);
        float r_next = r[b * TH + inext];
        float wpe_a  = wpe[(i + 1) * DD + lane];
        float wpe_b  = wpe[(i + 1) * DD + 64 + lane];

        for (int l = 0; l < NL; l++) {
            f16* Krow = Kb + ((size_t)l * TCAP + i) * DD;
            f16* Vrow = Vb + ((size_t)l * TCAP + i) * DD;
            const f16* Kl = Kb + (size_t)l * TCAP * DD;
            const f16* Vl = Vb + (size_t)l * TCAP * DD;

            // ================= Phase A: LN1(inline) + qkv =================
            // waves 4..7: prefetch K/V rows for phase B (issued first)
            f16x8 kreg[8], vreg[8];
            if (wid >= 4) {
                int j0 = (lane < i) ? lane : i;
                int j1 = (lane + 64 < i) ? (lane + 64) : i;
                const f16* K0p = Kl + (size_t)j0 * DD + hh * DHD;
                const f16* K1p = Kl + (size_t)j1 * DD + hh * DHD;
                #pragma unroll
                for (int g = 0; g < 4; g++) {
                    kreg[g]     = *(const f16x8*)(K0p + g * 8);
                    kreg[4 + g] = *(const f16x8*)(K1p + g * 8);
                }
                const f16* Vp = Vl + hh * DHD + vcg * 8;
                #pragma unroll
                for (int t = 0; t < 8; t++)
                    vreg[t] = *(const f16x8*)(Vp + (size_t)(vjs * 8 + t) * DD);
            }
            if (wid < 6) {
                float v0 = x[lane], v1 = x[lane + 64];
                float sm = wave_xor_sum(v0 + v1);
                float sq = wave_xor_sum(v0 * v0 + v1 * v1);
                float m  = sm * (1.f / DD);
                float rs = rsqrtf(sq * (1.f / DD) - m * m + 1e-5f);
                float hk[16];
                #pragma unroll
                for (int t = 0; t < 4; t++) {
                    float4 xx = *(const float4*)&x[k0q + 4 * t];
                    float4 ww = *(const float4*)&c_ln1w[l][k0q + 4 * t];
                    float4 bb = *(const float4*)&c_ln1b[l][k0q + 4 * t];
                    hk[4 * t + 0] = (xx.x - m) * rs * ww.x + bb.x;
                    hk[4 * t + 1] = (xx.y - m) * rs * ww.y + bb.y;
                    hk[4 * t + 2] = (xx.z - m) * rs * ww.z + bb.z;
                    hk[4 * t + 3] = (xx.w - m) * rs * ww.w + bb.w;
                }
                float acc[8] = {0.f,0.f,0.f,0.f,0.f,0.f,0.f,0.f};
                #pragma unroll
                for (int k = 0; k < 16; k++) {
                    f16x8 w = wq[k];
                    float hkk = hk[k];
                    #pragma unroll
                    for (int j = 0; j < 8; j++) acc[j] += hkk * (float)w[j];
                }
                #pragma unroll
                for (int off = 8; off <= 32; off <<= 1) {
                    #pragma unroll
                    for (int j = 0; j < 8; j++) acc[j] += __shfl_xor(acc[j], off);
                }
                if (ksq == 0) {
                    if (cbq < DD) {
                        #pragma unroll
                        for (int j = 0; j < 8; j++) qv[cbq + j] = acc[j] + c_qkvb[l][cbq + j];
                    } else if (cbq < 2 * DD) {
                        f16x8 kv;
                        #pragma unroll
                        for (int j = 0; j < 8; j++) kv[j] = (f16)(acc[j] + c_qkvb[l][cbq + j]);
                        *(f16x8*)(Krow + (cbq - DD)) = kv;
                    } else {
                        f16x8 vv;
                        #pragma unroll
                        for (int j = 0; j < 8; j++) vv[j] = (f16)(acc[j] + c_qkvb[l][cbq + j]);
                        *(f16x8*)(Vrow + (cbq - 2 * DD)) = vv;
                    }
                }
            }
            __syncthreads();

            // ========== Phase B: attn (waves 4..7); prefetch wp4+wf =========
            // fresh row-i K/V (written last phase; L2-hot) issued first
            f16x8 kfr[4]; f16x8 vi;
            if (wid >= 4) {
                #pragma unroll
                for (int g = 0; g < 4; g++)
                    kfr[g] = *(const f16x8*)(Kl + (size_t)i * DD + hh * DHD + g * 8);
                vi = *(const f16x8*)(Vl + (size_t)i * DD + hh * DHD + vcg * 8);
            }
            f16x8 wp4[4];
            {
                const f16* W = Wp + (size_t)l * DD * DD + cb2;
                #pragma unroll
                for (int k = 0; k < 4; k++) wp4[k] = *(const f16x8*)(W + (size_t)(ks2 * 4 + k) * DD);
            }
            f16x8 wf[16];
            {
                const f16* W = Wf + (size_t)l * DD * D4 + cbq;
                #pragma unroll
                for (int k = 0; k < 16; k++) wf[k] = *(const f16x8*)(W + (size_t)(k0q + k) * D4);
            }
            if (wid >= 4) {
                const bool ok0 = (lane <= i), ok1 = (lane + 64 <= i);
                float d0 = 0.f, d1 = 0.f;
                #pragma unroll
                for (int g = 0; g < 4; g++) {
                    f16x8 ka  = (lane      >= i) ? kfr[g] : kreg[g];
                    f16x8 kb2 = (lane + 64 >= i) ? kfr[g] : kreg[4 + g];
                    float4 qa = *(const float4*)&qv[hh * DHD + g * 8];
                    float4 qb = *(const float4*)&qv[hh * DHD + g * 8 + 4];
                    d0 += qa.x*(float)ka[0] + qa.y*(float)ka[1] + qa.z*(float)ka[2] + qa.w*(float)ka[3]
                        + qb.x*(float)ka[4] + qb.y*(float)ka[5] + qb.z*(float)ka[6] + qb.w*(float)ka[7];
                    d1 += qa.x*(float)kb2[0] + qa.y*(float)kb2[1] + qa.z*(float)kb2[2] + qa.w*(float)kb2[3]
                        + qb.x*(float)kb2[4] + qb.y*(float)kb2[5] + qb.z*(float)kb2[6] + qb.w*(float)kb2[7];
                }
                const float sscale = 0.17677669529663687f;
                float s0 = ok0 ? d0 * sscale : -1e30f;
                float s1 = ok1 ? d1 * sscale : -1e30f;
                float mx = wave_xor_max(fmaxf(s0, s1));
                float e0 = ok0 ? expf(s0 - mx) : 0.f;
                float e1 = ok1 ? expf(s1 - mx) : 0.f;
                float inv = 1.f / wave_xor_sum(e0 + e1);
                sc[hh][lane]      = e0 * inv;
                sc[hh][lane + 64] = e1 * inv;
                __builtin_amdgcn_wave_barrier();   // compiler fence: sc write -> read (same wave)
                // AV
                const int ja = vjs * 8;
                float4 pa = *(const float4*)&sc[hh][ja];
                float4 pb = *(const float4*)&sc[hh][ja + 4];
                float pv[8] = {pa.x, pa.y, pa.z, pa.w, pb.x, pb.y, pb.z, pb.w};
                float a[8] = {0.f,0.f,0.f,0.f,0.f,0.f,0.f,0.f};
                #pragma unroll
                for (int t = 0; t < 8; t++) {
                    f16x8 vv = (ja + t == i) ? vi : vreg[t];
                    float p = pv[t];
                    #pragma unroll
                    for (int u = 0; u < 8; u++) a[u] += p * (float)vv[u];
                }
                #pragma unroll
                for (int off = 4; off <= 32; off <<= 1) {
                    #pragma unroll
                    for (int u = 0; u < 8; u++) a[u] += __shfl_xor(a[u], off);
                }
                if (vjs == 0) {
                    #pragma unroll
                    for (int u = 0; u < 8; u++) o[hh * DHD + vcg * 8 + u] = a[u];
                }
            }
            __syncthreads();

            // ============ Phase C: proj + residual; prefetch wf2 ============
            f16x8 wf2[16];
            {
                const f16* W = Wf2 + (size_t)l * D4 * DD + cb2;
                #pragma unroll
                for (int k = 0; k < 16; k++) wf2[k] = *(const f16x8*)(W + (size_t)(ks2 * 16 + k) * DD);
            }
            {
                float4 ov = *(const float4*)&o[ks2 * 4];
                float oo[4] = {ov.x, ov.y, ov.z, ov.w};
                float acc[8] = {0.f,0.f,0.f,0.f,0.f,0.f,0.f,0.f};
                #pragma unroll
                for (int k = 0; k < 4; k++) {
                    f16x8 w = wp4[k];
                    float ok_ = oo[k];
                    #pragma unroll
                    for (int j = 0; j < 8; j++) acc[j] += ok_ * (float)w[j];
                }
                #pragma unroll
                for (int off = 2; off <= 32; off <<= 1) {
                    #pragma unroll
                    for (int j = 0; j < 8; j++) acc[j] += __shfl_xor(acc[j], off);
                }
                if (ks2 == 0) {
                    #pragma unroll
                    for (int j = 0; j < 8; j++) x[cb2 + j] += acc[j] + c_projb[l][cb2 + j];
                }
            }
            __syncthreads();

            // ============== Phase D: LN2(inline) + fc + gelu ===============
            {
                float v0 = x[lane], v1 = x[lane + 64];
                float sm = wave_xor_sum(v0 + v1);
                float sq = wave_xor_sum(v0 * v0 + v1 * v1);
                float m  = sm * (1.f / DD);
                float rs = rsqrtf(sq * (1.f / DD) - m * m + 1e-5f);
                float hk[16];
                #pragma unroll
                for (int t = 0; t < 4; t++) {
                    float4 xx = *(const float4*)&x[k0q + 4 * t];
                    float4 ww = *(const float4*)&c_ln2w[l][k0q + 4 * t];
                    float4 bb = *(const float4*)&c_ln2b[l][k0q + 4 * t];
                    hk[4 * t + 0] = (xx.x - m) * rs * ww.x + bb.x;
                    hk[4 * t + 1] = (xx.y - m) * rs * ww.y + bb.y;
                    hk[4 * t + 2] = (xx.z - m) * rs * ww.z + bb.z;
                    hk[4 * t + 3] = (xx.w - m) * rs * ww.w + bb.w;
                }
                float acc[8] = {0.f,0.f,0.f,0.f,0.f,0.f,0.f,0.f};
                #pragma unroll
                for (int k = 0; k < 16; k++) {
                    f16x8 w = wf[k];
                    float hkk = hk[k];
                    #pragma unroll
                    for (int j = 0; j < 8; j++) acc[j] += hkk * (float)w[j];
                }
                #pragma unroll
                for (int off = 8; off <= 32; off <<= 1) {
                    #pragma unroll
                    for (int j = 0; j < 8; j++) acc[j] += __shfl_xor(acc[j], off);
                }
                if (ksq == 0) {
                    #pragma unroll
                    for (int j = 0; j < 8; j++) hmid[cbq + j] = gelu_tanh(acc[j] + c_fcb[l][cbq + j]);
                }
            }
            __syncthreads();

            // ===== Phase E: fc2 + residual; prefetch wq(next layer) ========
            {
                const int ln = (l + 1 == NL) ? 0 : (l + 1);
                if (wid < 6) {
                    const f16* W = Wq + (size_t)ln * DD * D3 + cbq;
                    #pragma unroll
                    for (int k = 0; k < 16; k++) wq[k] = *(const f16x8*)(W + (size_t)(k0q + k) * D3);
                }
            }
            {
                float mk[16];
                #pragma unroll
                for (int t = 0; t < 4; t++) {
                    float4 mm = *(const float4*)&hmid[ks2 * 16 + 4 * t];
                    mk[4 * t + 0] = mm.x; mk[4 * t + 1] = mm.y;
                    mk[4 * t + 2] = mm.z; mk[4 * t + 3] = mm.w;
                }
                float acc[8] = {0.f,0.f,0.f,0.f,0.f,0.f,0.f,0.f};
                #pragma unroll
                for (int k = 0; k < 16; k++) {
                    f16x8 w = wf2[k];
                    float mkk = mk[k];
                    #pragma unroll
                    for (int j = 0; j < 8; j++) acc[j] += mkk * (float)w[j];
                }
                #pragma unroll
                for (int off = 2; off <= 32; off <<= 1) {
                    #pragma unroll
                    for (int j = 0; j < 8; j++) acc[j] += __shfl_xor(acc[j], off);
                }
                if (ks2 == 0) {
                    #pragma unroll
                    for (int j = 0; j < 8; j++) x[cb2 + j] += acc[j] + c_fc2b[l][cb2 + j];
                }
            }
            __syncthreads();
        } // layers

        // ==== head + state update + x-init for step i+1 (wave 0 only) ====
        if (wid == 0) {
            float v0 = x[lane], v1 = x[lane + 64];
            float sm = wave_xor_sum(v0 + v1);
            float sq = wave_xor_sum(v0 * v0 + v1 * v1);
            float m  = sm * (1.f / DD);
            float rs = rsqrtf(sq * (1.f / DD) - m * m + 1e-5f);
            float h0 = (v0 - m) * rs * c_lnfw[lane]      + c_lnfb[lane];
            float h1 = (v1 - m) * rs * c_lnfw[lane + 64] + c_lnfb[lane + 64];
            float v  = wave_xor_sum(h0 * c_headw[lane] + h1 * c_headw[lane + 64]);
            float un = v + hb;
            float s  = s_reg;
            if (lane == 0) Y[b * TH + i] = s;
            float sn = s + (-p0 * s + p1 * tanhf(un));
            s_reg = sn;
            float e = r_next - sn;
            x[lane]      = e * c_wte0[lane]      + un * c_wte1[lane]      + c_wteb[lane]      + wpe_a;
            x[lane + 64] = e * c_wte0[lane + 64] + un * c_wte1[lane + 64] + c_wteb[lane + 64] + wpe_b;
        }
        __syncthreads();
    } // steps
}

extern "C" void kernel_launch(void* const* d_in, const int* in_sizes, int n_in,
                              void* d_out, int out_size, void* d_ws, size_t ws_size,
                              hipStream_t stream) {
    const float* data   = (const float*)d_in[0];
    const float* r      = (const float*)d_in[1];
    const float* wte_w  = (const float*)d_in[2];
    const float* wte_b  = (const float*)d_in[3];
    const float* wpe    = (const float*)d_in[4];
    const float* ln1_w  = (const float*)d_in[5];
    const float* ln1_b  = (const float*)d_in[6];
    const float* ln2_w  = (const float*)d_in[7];
    const float* ln2_b  = (const float*)d_in[8];
    const float* qkv_w  = (const float*)d_in[9];
    const float* qkv_b  = (const float*)d_in[10];
    const float* proj_w = (const float*)d_in[11];
    const float* proj_b = (const float*)d_in[12];
    const float* fc_w   = (const float*)d_in[13];
    const float* fc_b   = (const float*)d_in[14];
    const float* fc2_w  = (const float*)d_in[15];
    const float* fc2_b  = (const float*)d_in[16];
    const float* lnf_w  = (const float*)d_in[17];
    const float* lnf_b  = (const float*)d_in[18];
    const float* head_w = (const float*)d_in[19];
    const float* head_b = (const float*)d_in[20];

    f16* wsp = (f16*)d_ws;
    f16* Wq  = wsp;
    f16* Wp  = Wq  + NL * DD * D3;
    f16* Wf  = Wp  + NL * DD * DD;
    f16* Wf2 = Wf  + NL * DD * D4;
    f16* Kc  = Wf2 + NL * D4 * DD;
    f16* Vc  = Kc  + (size_t)NB * NL * TCAP * DD;

    const int n_w = NL * DD * D3 + NL * DD * DD + NL * DD * D4 + NL * D4 * DD;
    prep_kernel<<<(n_w + 255) / 256, 256, 0, stream>>>(qkv_w, proj_w, fc_w, fc2_w, Wq);

    gpt_loop<<<NB, 512, 0, stream>>>(
        data, r, wte_w, wte_b, wpe, ln1_w, ln1_b, ln2_w, ln2_b,
        qkv_b, proj_b, fc_b, fc2_b, lnf_w, lnf_b, head_w, head_b,
        Wq, Wp, Wf, Wf2, Kc, Vc, (float*)d_out);
}

// Round 2
// 16732.390 us; speedup vs baseline: 1.0036x; 1.0036x over previous
//
#include <hip/hip_runtime.h>
#include <math.h>

#define NB   32    // batch
#define TH   128   // scan steps
#define NL   6     // layers
#define DD   128   // model dim
#define NH   4     // heads
#define DHD  32    // head dim
#define TCAP 128   // max cached tokens
#define D3   384
#define D4   512

typedef _Float16 f16;
typedef _Float16 f16x8 __attribute__((ext_vector_type(8)));

// fp32 -> fp16 (RNE) weight conversion into workspace
__global__ void prep_kernel(const float* __restrict__ qkv, const float* __restrict__ proj,
                            const float* __restrict__ fc,  const float* __restrict__ fc2,
                            f16* __restrict__ out) {
    int i = blockIdx.x * blockDim.x + threadIdx.x;
    const int n0 = NL * DD * D3, n1 = NL * DD * DD, n2 = NL * DD * D4, n3 = NL * D4 * DD;
    const int total = n0 + n1 + n2 + n3;
    if (i >= total) return;
    float v;
    if (i < n0)                 v = qkv[i];
    else if (i < n0 + n1)       v = proj[i - n0];
    else if (i < n0 + n1 + n2)  v = fc[i - n0 - n1];
    else                        v = fc2[i - n0 - n1 - n2];
    out[i] = (f16)v;
}

__device__ __forceinline__ float wave_xor_sum(float v) {
    #pragma unroll
    for (int off = 1; off < 64; off <<= 1) v += __shfl_xor(v, off);
    return v;
}
__device__ __forceinline__ float wave_xor_max(float v) {
    #pragma unroll
    for (int off = 1; off < 64; off <<= 1) v = fmaxf(v, __shfl_xor(v, off));
    return v;
}
__device__ __forceinline__ float gelu_tanh(float v) {
    float t = v * v * v;
    return 0.5f * v * (1.f + tanhf(0.7978845608028654f * (v + 0.044715f * t)));
}

// One workgroup (512 threads) per batch element; 128 KV-cached decode steps.
// 5 barrier phases per layer (A:qkv+LN1, B:attn, C:proj, D:fc+LN2, E:fc2).
// Every weight/KV tile is prefetched into registers one phase ahead: the
// compiler's vmcnt(0) drain at each __syncthreads() completes the loads
// exactly when the next phase consumes them, hiding L2/HBM latency behind
// the previous phase's compute.
// __launch_bounds__(512, 2): 8 waves = 2/SIMD -> 256-VGPR cap. R1's bare
// (512) capped at 128 VGPR and spilled all prefetch arrays to scratch
// (FETCH 217MB->1.1GB, WRITE 12.5->151MB). One block/CU is all this
// 32-block grid can use, so trading occupancy headroom for registers is free.
__global__ __launch_bounds__(512, 2) void gpt_loop(
    const float* __restrict__ data,  const float* __restrict__ r,
    const float* __restrict__ wte_w, const float* __restrict__ wte_b,
    const float* __restrict__ wpe,
    const float* __restrict__ ln1_w, const float* __restrict__ ln1_b,
    const float* __restrict__ ln2_w, const float* __restrict__ ln2_b,
    const float* __restrict__ qkv_b, const float* __restrict__ proj_b,
    const float* __restrict__ fc_b,  const float* __restrict__ fc2_b,
    const float* __restrict__ lnf_w, const float* __restrict__ lnf_b,
    const float* __restrict__ head_w,const float* __restrict__ head_b,
    const f16* __restrict__ Wq, const f16* __restrict__ Wp,
    const f16* __restrict__ Wf, const f16* __restrict__ Wf2,
    f16* __restrict__ Kc, f16* __restrict__ Vc,
    float* __restrict__ Y)
{
    const int b    = blockIdx.x;
    const int tid  = threadIdx.x;
    const int lane = tid & 63;
    const int wid  = tid >> 6;

    __shared__ __align__(16) float x[DD], qv[DD], o[DD], hmid[D4];
    __shared__ __align__(16) float sc[NH][TCAP];
    __shared__ __align__(16) float c_ln1w[NL][DD], c_ln1b[NL][DD], c_ln2w[NL][DD], c_ln2b[NL][DD];
    __shared__ __align__(16) float c_qkvb[NL][D3], c_projb[NL][DD], c_fcb[NL][D4], c_fc2b[NL][DD];
    __shared__ __align__(16) float c_lnfw[DD], c_lnfb[DD], c_headw[DD], c_wte0[DD], c_wte1[DD], c_wteb[DD];

    const float p0 = data[b * 2 + 0];
    const float p1 = data[b * 2 + 1];
    const float hb = head_b[0];

    f16* Kb = Kc + (size_t)b * NL * TCAP * DD;
    f16* Vb = Vc + (size_t)b * NL * TCAP * DD;

    for (int idx = tid; idx < NL * DD; idx += 512) {
        int l = idx / DD, d = idx % DD;
        c_ln1w[l][d] = ln1_w[idx]; c_ln1b[l][d] = ln1_b[idx];
        c_ln2w[l][d] = ln2_w[idx]; c_ln2b[l][d] = ln2_b[idx];
        c_projb[l][d] = proj_b[idx]; c_fc2b[l][d] = fc2_b[idx];
    }
    for (int idx = tid; idx < NL * D3; idx += 512) c_qkvb[idx / D3][idx % D3] = qkv_b[idx];
    for (int idx = tid; idx < NL * D4; idx += 512) c_fcb[idx / D4][idx % D4] = fc_b[idx];
    if (tid < DD) {
        c_lnfw[tid] = lnf_w[tid]; c_lnfb[tid] = lnf_b[tid]; c_headw[tid] = head_w[tid];
        c_wte0[tid] = wte_w[tid]; c_wte1[tid] = wte_w[DD + tid]; c_wteb[tid] = wte_b[tid];
    }
    // zero-init this block's KV cache: rows > current step then contribute
    // exact 0 to AV, making full-width register prefetch safe.
    {
        float4 z4 = make_float4(0.f, 0.f, 0.f, 0.f);
        float4* K4 = (float4*)Kb; float4* V4 = (float4*)Vb;
        const int n4 = NL * TCAP * DD * 2 / 16;
        for (int idx = tid; idx < n4; idx += 512) { K4[idx] = z4; V4[idx] = z4; }
    }
    __syncthreads();

    // ---- prologue: state + x-init for step 0 + wq(layer 0) prefetch ----
    float s_reg = 0.f;                       // state lives in wave-0 registers
    if (wid == 0) {
        float e0 = r[b * TH + 0];            // s=0, u=0 at step 0
        x[lane]      = e0 * c_wte0[lane]      + c_wteb[lane]      + wpe[lane];
        x[lane + 64] = e0 * c_wte0[lane + 64] + c_wteb[lane + 64] + wpe[64 + lane];
    }

    const int cgq = lane & 7, ksq = lane >> 3;       // qkv/fc mapping: 8 cols x 8 k-splits
    const int cbq = wid * 64 + cgq * 8, k0q = ksq * 16;
    const int cg2 = lane & 1, ks2 = lane >> 1;       // proj/fc2 mapping
    const int cb2 = (wid * 2 + cg2) * 8;
    const int hh  = wid - 4;                          // head for waves 4..7
    const int vcg = lane & 3, vjs = lane >> 2;        // AV mapping: 4 col-groups x 16 j-splits

    f16x8 wq[16];
    if (wid < 6) {
        const f16* W = Wq + cbq;
        #pragma unroll
        for (int k = 0; k < 16; k++) wq[k] = *(const f16x8*)(W + (size_t)(k0q + k) * D3);
    }
    __syncthreads();

    for (int i = 0; i < TH; i++) {
        // step-top prefetches for the head/x-init phase (held in regs all step)
        const int inext = (i + 1 < TH) ? (i + 1) : (TH - 1);
        float r_next = r[b * TH + inext];
        float wpe_a  = wpe[(i + 1) * DD + lane];
        float wpe_b  = wpe[(i + 1) * DD + 64 + lane];

        for (int l = 0; l < NL; l++) {
            f16* Krow = Kb + ((size_t)l * TCAP + i) * DD;
            f16* Vrow = Vb + ((size_t)l * TCAP + i) * DD;
            const f16* Kl = Kb + (size_t)l * TCAP * DD;
            const f16* Vl = Vb + (size_t)l * TCAP * DD;

            // ================= Phase A: LN1(inline) + qkv =================
            // waves 4..7: prefetch K/V rows for phase B (issued first)
            f16x8 kreg[8], vreg[8];
            if (wid >= 4) {
                int j0 = (lane < i) ? lane : i;
                int j1 = (lane + 64 < i) ? (lane + 64) : i;
                const f16* K0p = Kl + (size_t)j0 * DD + hh * DHD;
                const f16* K1p = Kl + (size_t)j1 * DD + hh * DHD;
                #pragma unroll
                for (int g = 0; g < 4; g++) {
                    kreg[g]     = *(const f16x8*)(K0p + g * 8);
                    kreg[4 + g] = *(const f16x8*)(K1p + g * 8);
                }
                const f16* Vp = Vl + hh * DHD + vcg * 8;
                #pragma unroll
                for (int t = 0; t < 8; t++)
                    vreg[t] = *(const f16x8*)(Vp + (size_t)(vjs * 8 + t) * DD);
            }
            if (wid < 6) {
                float v0 = x[lane], v1 = x[lane + 64];
                float sm = wave_xor_sum(v0 + v1);
                float sq = wave_xor_sum(v0 * v0 + v1 * v1);
                float m  = sm * (1.f / DD);
                float rs = rsqrtf(sq * (1.f / DD) - m * m + 1e-5f);
                float hk[16];
                #pragma unroll
                for (int t = 0; t < 4; t++) {
                    float4 xx = *(const float4*)&x[k0q + 4 * t];
                    float4 ww = *(const float4*)&c_ln1w[l][k0q + 4 * t];
                    float4 bb = *(const float4*)&c_ln1b[l][k0q + 4 * t];
                    hk[4 * t + 0] = (xx.x - m) * rs * ww.x + bb.x;
                    hk[4 * t + 1] = (xx.y - m) * rs * ww.y + bb.y;
                    hk[4 * t + 2] = (xx.z - m) * rs * ww.z + bb.z;
                    hk[4 * t + 3] = (xx.w - m) * rs * ww.w + bb.w;
                }
                float acc[8] = {0.f,0.f,0.f,0.f,0.f,0.f,0.f,0.f};
                #pragma unroll
                for (int k = 0; k < 16; k++) {
                    f16x8 w = wq[k];
                    float hkk = hk[k];
                    #pragma unroll
                    for (int j = 0; j < 8; j++) acc[j] += hkk * (float)w[j];
                }
                #pragma unroll
                for (int off = 8; off <= 32; off <<= 1) {
                    #pragma unroll
                    for (int j = 0; j < 8; j++) acc[j] += __shfl_xor(acc[j], off);
                }
                if (ksq == 0) {
                    if (cbq < DD) {
                        #pragma unroll
                        for (int j = 0; j < 8; j++) qv[cbq + j] = acc[j] + c_qkvb[l][cbq + j];
                    } else if (cbq < 2 * DD) {
                        f16x8 kv;
                        #pragma unroll
                        for (int j = 0; j < 8; j++) kv[j] = (f16)(acc[j] + c_qkvb[l][cbq + j]);
                        *(f16x8*)(Krow + (cbq - DD)) = kv;
                    } else {
                        f16x8 vv;
                        #pragma unroll
                        for (int j = 0; j < 8; j++) vv[j] = (f16)(acc[j] + c_qkvb[l][cbq + j]);
                        *(f16x8*)(Vrow + (cbq - 2 * DD)) = vv;
                    }
                }
            }
            __syncthreads();

            // ========== Phase B: attn (waves 4..7); prefetch wp4+wf =========
            // fresh row-i K/V (written last phase; L2-hot) issued first
            f16x8 kfr[4]; f16x8 vi;
            if (wid >= 4) {
                #pragma unroll
                for (int g = 0; g < 4; g++)
                    kfr[g] = *(const f16x8*)(Kl + (size_t)i * DD + hh * DHD + g * 8);
                vi = *(const f16x8*)(Vl + (size_t)i * DD + hh * DHD + vcg * 8);
            }
            f16x8 wp4[4];
            {
                const f16* W = Wp + (size_t)l * DD * DD + cb2;
                #pragma unroll
                for (int k = 0; k < 4; k++) wp4[k] = *(const f16x8*)(W + (size_t)(ks2 * 4 + k) * DD);
            }
            f16x8 wf[16];
            {
                const f16* W = Wf + (size_t)l * DD * D4 + cbq;
                #pragma unroll
                for (int k = 0; k < 16; k++) wf[k] = *(const f16x8*)(W + (size_t)(k0q + k) * D4);
            }
            if (wid >= 4) {
                const bool ok0 = (lane <= i), ok1 = (lane + 64 <= i);
                float d0 = 0.f, d1 = 0.f;
                #pragma unroll
                for (int g = 0; g < 4; g++) {
                    f16x8 ka  = (lane      >= i) ? kfr[g] : kreg[g];
                    f16x8 kb2 = (lane + 64 >= i) ? kfr[g] : kreg[4 + g];
                    float4 qa = *(const float4*)&qv[hh * DHD + g * 8];
                    float4 qb = *(const float4*)&qv[hh * DHD + g * 8 + 4];
                    d0 += qa.x*(float)ka[0] + qa.y*(float)ka[1] + qa.z*(float)ka[2] + qa.w*(float)ka[3]
                        + qb.x*(float)ka[4] + qb.y*(float)ka[5] + qb.z*(float)ka[6] + qb.w*(float)ka[7];
                    d1 += qa.x*(float)kb2[0] + qa.y*(float)kb2[1] + qa.z*(float)kb2[2] + qa.w*(float)kb2[3]
                        + qb.x*(float)kb2[4] + qb.y*(float)kb2[5] + qb.z*(float)kb2[6] + qb.w*(float)kb2[7];
                }
                const float sscale = 0.17677669529663687f;
                float s0 = ok0 ? d0 * sscale : -1e30f;
                float s1 = ok1 ? d1 * sscale : -1e30f;
                float mx = wave_xor_max(fmaxf(s0, s1));
                float e0 = ok0 ? expf(s0 - mx) : 0.f;
                float e1 = ok1 ? expf(s1 - mx) : 0.f;
                float inv = 1.f / wave_xor_sum(e0 + e1);
                sc[hh][lane]      = e0 * inv;
                sc[hh][lane + 64] = e1 * inv;
                __builtin_amdgcn_wave_barrier();   // compiler fence: sc write -> read (same wave)
                // AV
                const int ja = vjs * 8;
                float4 pa = *(const float4*)&sc[hh][ja];
                float4 pb = *(const float4*)&sc[hh][ja + 4];
                float pv[8] = {pa.x, pa.y, pa.z, pa.w, pb.x, pb.y, pb.z, pb.w};
                float a[8] = {0.f,0.f,0.f,0.f,0.f,0.f,0.f,0.f};
                #pragma unroll
                for (int t = 0; t < 8; t++) {
                    f16x8 vv = (ja + t == i) ? vi : vreg[t];
                    float p = pv[t];
                    #pragma unroll
                    for (int u = 0; u < 8; u++) a[u] += p * (float)vv[u];
                }
                #pragma unroll
                for (int off = 4; off <= 32; off <<= 1) {
                    #pragma unroll
                    for (int u = 0; u < 8; u++) a[u] += __shfl_xor(a[u], off);
                }
                if (vjs == 0) {
                    #pragma unroll
                    for (int u = 0; u < 8; u++) o[hh * DHD + vcg * 8 + u] = a[u];
                }
            }
            __syncthreads();

            // ============ Phase C: proj + residual; prefetch wf2 ============
            f16x8 wf2[16];
            {
                const f16* W = Wf2 + (size_t)l * D4 * DD + cb2;
                #pragma unroll
                for (int k = 0; k < 16; k++) wf2[k] = *(const f16x8*)(W + (size_t)(ks2 * 16 + k) * DD);
            }
            {
                float4 ov = *(const float4*)&o[ks2 * 4];
                float oo[4] = {ov.x, ov.y, ov.z, ov.w};
                float acc[8] = {0.f,0.f,0.f,0.f,0.f,0.f,0.f,0.f};
                #pragma unroll
                for (int k = 0; k < 4; k++) {
                    f16x8 w = wp4[k];
                    float ok_ = oo[k];
                    #pragma unroll
                    for (int j = 0; j < 8; j++) acc[j] += ok_ * (float)w[j];
                }
                #pragma unroll
                for (int off = 2; off <= 32; off <<= 1) {
                    #pragma unroll
                    for (int j = 0; j < 8; j++) acc[j] += __shfl_xor(acc[j], off);
                }
                if (ks2 == 0) {
                    #pragma unroll
                    for (int j = 0; j < 8; j++) x[cb2 + j] += acc[j] + c_projb[l][cb2 + j];
                }
            }
            __syncthreads();

            // ============== Phase D: LN2(inline) + fc + gelu ===============
            {
                float v0 = x[lane], v1 = x[lane + 64];
                float sm = wave_xor_sum(v0 + v1);
                float sq = wave_xor_sum(v0 * v0 + v1 * v1);
                float m  = sm * (1.f / DD);
                float rs = rsqrtf(sq * (1.f / DD) - m * m + 1e-5f);
                float hk[16];
                #pragma unroll
                for (int t = 0; t < 4; t++) {
                    float4 xx = *(const float4*)&x[k0q + 4 * t];
                    float4 ww = *(const float4*)&c_ln2w[l][k0q + 4 * t];
                    float4 bb = *(const float4*)&c_ln2b[l][k0q + 4 * t];
                    hk[4 * t + 0] = (xx.x - m) * rs * ww.x + bb.x;
                    hk[4 * t + 1] = (xx.y - m) * rs * ww.y + bb.y;
                    hk[4 * t + 2] = (xx.z - m) * rs * ww.z + bb.z;
                    hk[4 * t + 3] = (xx.w - m) * rs * ww.w + bb.w;
                }
                float acc[8] = {0.f,0.f,0.f,0.f,0.f,0.f,0.f,0.f};
                #pragma unroll
                for (int k = 0; k < 16; k++) {
                    f16x8 w = wf[k];
                    float hkk = hk[k];
                    #pragma unroll
                    for (int j = 0; j < 8; j++) acc[j] += hkk * (float)w[j];
                }
                #pragma unroll
                for (int off = 8; off <= 32; off <<= 1) {
                    #pragma unroll
                    for (int j = 0; j < 8; j++) acc[j] += __shfl_xor(acc[j], off);
                }
                if (ksq == 0) {
                    #pragma unroll
                    for (int j = 0; j < 8; j++) hmid[cbq + j] = gelu_tanh(acc[j] + c_fcb[l][cbq + j]);
                }
            }
            __syncthreads();

            // ===== Phase E: fc2 + residual; prefetch wq(next layer) ========
            {
                const int ln = (l + 1 == NL) ? 0 : (l + 1);
                if (wid < 6) {
                    const f16* W = Wq + (size_t)ln * DD * D3 + cbq;
                    #pragma unroll
                    for (int k = 0; k < 16; k++) wq[k] = *(const f16x8*)(W + (size_t)(k0q + k) * D3);
                }
            }
            {
                float mk[16];
                #pragma unroll
                for (int t = 0; t < 4; t++) {
                    float4 mm = *(const float4*)&hmid[ks2 * 16 + 4 * t];
                    mk[4 * t + 0] = mm.x; mk[4 * t + 1] = mm.y;
                    mk[4 * t + 2] = mm.z; mk[4 * t + 3] = mm.w;
                }
                float acc[8] = {0.f,0.f,0.f,0.f,0.f,0.f,0.f,0.f};
                #pragma unroll
                for (int k = 0; k < 16; k++) {
                    f16x8 w = wf2[k];
                    float mkk = mk[k];
                    #pragma unroll
                    for (int j = 0; j < 8; j++) acc[j] += mkk * (float)w[j];
                }
                #pragma unroll
                for (int off = 2; off <= 32; off <<= 1) {
                    #pragma unroll
                    for (int j = 0; j < 8; j++) acc[j] += __shfl_xor(acc[j], off);
                }
                if (ks2 == 0) {
                    #pragma unroll
                    for (int j = 0; j < 8; j++) x[cb2 + j] += acc[j] + c_fc2b[l][cb2 + j];
                }
            }
            __syncthreads();
        } // layers

        // ==== head + state update + x-init for step i+1 (wave 0 only) ====
        if (wid == 0) {
            float v0 = x[lane], v1 = x[lane + 64];
            float sm = wave_xor_sum(v0 + v1);
            float sq = wave_xor_sum(v0 * v0 + v1 * v1);
            float m  = sm * (1.f / DD);
            float rs = rsqrtf(sq * (1.f / DD) - m * m + 1e-5f);
            float h0 = (v0 - m) * rs * c_lnfw[lane]      + c_lnfb[lane];
            float h1 = (v1 - m) * rs * c_lnfw[lane + 64] + c_lnfb[lane + 64];
            float v  = wave_xor_sum(h0 * c_headw[lane] + h1 * c_headw[lane + 64]);
            float un = v + hb;
            float s  = s_reg;
            if (lane == 0) Y[b * TH + i] = s;
            float sn = s + (-p0 * s + p1 * tanhf(un));
            s_reg = sn;
            float e = r_next - sn;
            x[lane]      = e * c_wte0[lane]      + un * c_wte1[lane]      + c_wteb[lane]      + wpe_a;
            x[lane + 64] = e * c_wte0[lane + 64] + un * c_wte1[lane + 64] + c_wteb[lane + 64] + wpe_b;
        }
        __syncthreads();
    } // steps
}

extern "C" void kernel_launch(void* const* d_in, const int* in_sizes, int n_in,
                              void* d_out, int out_size, void* d_ws, size_t ws_size,
                              hipStream_t stream) {
    const float* data   = (const float*)d_in[0];
    const float* r      = (const float*)d_in[1];
    const float* wte_w  = (const float*)d_in[2];
    const float* wte_b  = (const float*)d_in[3];
    const float* wpe    = (const float*)d_in[4];
    const float* ln1_w  = (const float*)d_in[5];
    const float* ln1_b  = (const float*)d_in[6];
    const float* ln2_w  = (const float*)d_in[7];
    const float* ln2_b  = (const float*)d_in[8];
    const float* qkv_w  = (const float*)d_in[9];
    const float* qkv_b  = (const float*)d_in[10];
    const float* proj_w = (const float*)d_in[11];
    const float* proj_b = (const float*)d_in[12];
    const float* fc_w   = (const float*)d_in[13];
    const float* fc_b   = (const float*)d_in[14];
    const float* fc2_w  = (const float*)d_in[15];
    const float* fc2_b  = (const float*)d_in[16];
    const float* lnf_w  = (const float*)d_in[17];
    const float* lnf_b  = (const float*)d_in[18];
    const float* head_w = (const float*)d_in[19];
    const float* head_b = (const float*)d_in[20];

    f16* wsp = (f16*)d_ws;
    f16* Wq  = wsp;
    f16* Wp  = Wq  + NL * DD * D3;
    f16* Wf  = Wp  + NL * DD * DD;
    f16* Wf2 = Wf  + NL * DD * D4;
    f16* Kc  = Wf2 + NL * D4 * DD;
    f16* Vc  = Kc  + (size_t)NB * NL * TCAP * DD;

    const int n_w = NL * DD * D3 + NL * DD * DD + NL * DD * D4 + NL * D4 * DD;
    prep_kernel<<<(n_w + 255) / 256, 256, 0, stream>>>(qkv_w, proj_w, fc_w, fc2_w, Wq);

    gpt_loop<<<NB, 512, 0, stream>>>(
        data, r, wte_w, wte_b, wpe, ln1_w, ln1_b, ln2_w, ln2_b,
        qkv_b, proj_b, fc_b, fc2_b, lnf_w, lnf_b, head_w, head_b,
        Wq, Wp, Wf, Wf2, Kc, Vc, (float*)d_out);
}

// Round 3
// 9773.232 us; speedup vs baseline: 1.7183x; 1.7121x over previous
//
#include <hip/hip_runtime.h>
#include <math.h>

#define NB   32    // batch
#define TH   128   // scan steps
#define NL   6     // layers
#define DD   128   // model dim
#define NH   4     // heads
#define DHD  32    // head dim
#define TCAP 128   // max cached tokens
#define D3   384
#define D4   512

typedef _Float16 f16;
typedef _Float16 f16x8 __attribute__((ext_vector_type(8)));

// fp32 -> fp16 (RNE) weight conversion into workspace
__global__ void prep_kernel(const float* __restrict__ qkv, const float* __restrict__ proj,
                            const float* __restrict__ fc,  const float* __restrict__ fc2,
                            f16* __restrict__ out) {
    int i = blockIdx.x * blockDim.x + threadIdx.x;
    const int n0 = NL * DD * D3, n1 = NL * DD * DD, n2 = NL * DD * D4, n3 = NL * D4 * DD;
    const int total = n0 + n1 + n2 + n3;
    if (i >= total) return;
    float v;
    if (i < n0)                 v = qkv[i];
    else if (i < n0 + n1)       v = proj[i - n0];
    else if (i < n0 + n1 + n2)  v = fc[i - n0 - n1];
    else                        v = fc2[i - n0 - n1 - n2];
    out[i] = (f16)v;
}

__device__ __forceinline__ float wave_xor_sum(float v) {
    #pragma unroll
    for (int off = 1; off < 64; off <<= 1) v += __shfl_xor(v, off);
    return v;
}
__device__ __forceinline__ float wave_xor_max(float v) {
    #pragma unroll
    for (int off = 1; off < 64; off <<= 1) v = fmaxf(v, __shfl_xor(v, off));
    return v;
}
__device__ __forceinline__ float gelu_tanh(float v) {
    float t = v * v * v;
    return 0.5f * v * (1.f + tanhf(0.7978845608028654f * (v + 0.044715f * t)));
}

// One workgroup (512 threads) per batch element; 128 KV-cached decode steps.
// 5 barrier phases per layer (A:qkv+LN1, B:attn, C:proj, D:fc+LN2, E:fc2).
// WEIGHT tiles are prefetched into registers one phase ahead; each prefetch
// is issued AFTER the consuming FMA loop of its phase so the previous weight
// array is dead first (peak liveness ~140 regs — no spill even at a 128 cap).
// K/V are loaded in-phase with row index clamped to <= i (rows > i have
// softmax weight exactly 0, so clamped garbage contributes 0).
// amdgpu_waves_per_eu(2,2): pin 2 waves/SIMD -> 256-VGPR budget (R2's
// __launch_bounds__(512,2) did NOT reach the backend; VGPR stayed 128 and
// prefetch arrays spilled: WRITE_SIZE 147 MB, FETCH 1.1 GB).
__global__ __launch_bounds__(512) __attribute__((amdgpu_waves_per_eu(2, 2))) void gpt_loop(
    const float* __restrict__ data,  const float* __restrict__ r,
    const float* __restrict__ wte_w, const float* __restrict__ wte_b,
    const float* __restrict__ wpe,
    const float* __restrict__ ln1_w, const float* __restrict__ ln1_b,
    const float* __restrict__ ln2_w, const float* __restrict__ ln2_b,
    const float* __restrict__ qkv_b, const float* __restrict__ proj_b,
    const float* __restrict__ fc_b,  const float* __restrict__ fc2_b,
    const float* __restrict__ lnf_w, const float* __restrict__ lnf_b,
    const float* __restrict__ head_w,const float* __restrict__ head_b,
    const f16* __restrict__ Wq, const f16* __restrict__ Wp,
    const f16* __restrict__ Wf, const f16* __restrict__ Wf2,
    f16* __restrict__ Kc, f16* __restrict__ Vc,
    float* __restrict__ Y)
{
    const int b    = blockIdx.x;
    const int tid  = threadIdx.x;
    const int lane = tid & 63;
    const int wid  = tid >> 6;

    __shared__ __align__(16) float x[DD], qv[DD], o[DD], hmid[D4];
    __shared__ __align__(16) float sc[NH][TCAP];
    __shared__ __align__(16) float c_ln1w[NL][DD], c_ln1b[NL][DD], c_ln2w[NL][DD], c_ln2b[NL][DD];
    __shared__ __align__(16) float c_qkvb[NL][D3], c_projb[NL][DD], c_fcb[NL][D4], c_fc2b[NL][DD];
    __shared__ __align__(16) float c_lnfw[DD], c_lnfb[DD], c_headw[DD], c_wte0[DD], c_wte1[DD], c_wteb[DD];

    const float p0 = data[b * 2 + 0];
    const float p1 = data[b * 2 + 1];
    const float hb = head_b[0];

    f16* Kb = Kc + (size_t)b * NL * TCAP * DD;
    f16* Vb = Vc + (size_t)b * NL * TCAP * DD;

    for (int idx = tid; idx < NL * DD; idx += 512) {
        int l = idx / DD, d = idx % DD;
        c_ln1w[l][d] = ln1_w[idx]; c_ln1b[l][d] = ln1_b[idx];
        c_ln2w[l][d] = ln2_w[idx]; c_ln2b[l][d] = ln2_b[idx];
        c_projb[l][d] = proj_b[idx]; c_fc2b[l][d] = fc2_b[idx];
    }
    for (int idx = tid; idx < NL * D3; idx += 512) c_qkvb[idx / D3][idx % D3] = qkv_b[idx];
    for (int idx = tid; idx < NL * D4; idx += 512) c_fcb[idx / D4][idx % D4] = fc_b[idx];
    if (tid < DD) {
        c_lnfw[tid] = lnf_w[tid]; c_lnfb[tid] = lnf_b[tid]; c_headw[tid] = head_w[tid];
        c_wte0[tid] = wte_w[tid]; c_wte1[tid] = wte_w[DD + tid]; c_wteb[tid] = wte_b[tid];
    }
    __syncthreads();

    // ---- prologue: state + x-init for step 0 + wq(layer 0) prefetch ----
    float s_reg = 0.f;                       // state lives in wave-0 registers
    if (wid == 0) {
        float e0 = r[b * TH + 0];            // s=0, u=0 at step 0
        x[lane]      = e0 * c_wte0[lane]      + c_wteb[lane]      + wpe[lane];
        x[lane + 64] = e0 * c_wte0[lane + 64] + c_wteb[lane + 64] + wpe[64 + lane];
    }

    const int cgq = lane & 7, ksq = lane >> 3;       // qkv/fc mapping: 8 cols x 8 k-splits
    const int cbq = wid * 64 + cgq * 8, k0q = ksq * 16;
    const int cg2 = lane & 1, ks2 = lane >> 1;       // proj/fc2 mapping
    const int cb2 = (wid * 2 + cg2) * 8;
    const int hh  = wid - 4;                          // head for waves 4..7
    const int vcg = lane & 3, vjs = lane >> 2;        // AV mapping: 4 col-groups x 16 j-splits

    f16x8 wq[16];
    if (wid < 6) {
        const f16* W = Wq + cbq;
        #pragma unroll
        for (int k = 0; k < 16; k++) wq[k] = *(const f16x8*)(W + (size_t)(k0q + k) * D3);
    }
    __syncthreads();

    for (int i = 0; i < TH; i++) {
        // step-top prefetches for the head/x-init phase (held in regs all step)
        const int inext = (i + 1 < TH) ? (i + 1) : (TH - 1);
        float r_next = r[b * TH + inext];
        float wpe_a  = wpe[(i + 1) * DD + lane];
        float wpe_b  = wpe[(i + 1) * DD + 64 + lane];

        for (int l = 0; l < NL; l++) {
            f16* Krow = Kb + ((size_t)l * TCAP + i) * DD;
            f16* Vrow = Vb + ((size_t)l * TCAP + i) * DD;
            const f16* Kl = Kb + (size_t)l * TCAP * DD;
            const f16* Vl = Vb + (size_t)l * TCAP * DD;

            f16x8 wp4[4];      // filled in B, consumed in C
            f16x8 wf[16];      // filled in C, consumed in D
            f16x8 wf2[16];     // filled in D, consumed in E

            // ================= Phase A: LN1(inline) + qkv =================
            if (wid < 6) {
                float v0 = x[lane], v1 = x[lane + 64];
                float sm = wave_xor_sum(v0 + v1);
                float sq = wave_xor_sum(v0 * v0 + v1 * v1);
                float m  = sm * (1.f / DD);
                float rs = rsqrtf(sq * (1.f / DD) - m * m + 1e-5f);
                float hk[16];
                #pragma unroll
                for (int t = 0; t < 4; t++) {
                    float4 xx = *(const float4*)&x[k0q + 4 * t];
                    float4 ww = *(const float4*)&c_ln1w[l][k0q + 4 * t];
                    float4 bb = *(const float4*)&c_ln1b[l][k0q + 4 * t];
                    hk[4 * t + 0] = (xx.x - m) * rs * ww.x + bb.x;
                    hk[4 * t + 1] = (xx.y - m) * rs * ww.y + bb.y;
                    hk[4 * t + 2] = (xx.z - m) * rs * ww.z + bb.z;
                    hk[4 * t + 3] = (xx.w - m) * rs * ww.w + bb.w;
                }
                float acc[8] = {0.f,0.f,0.f,0.f,0.f,0.f,0.f,0.f};
                #pragma unroll
                for (int k = 0; k < 16; k++) {
                    f16x8 w = wq[k];
                    float hkk = hk[k];
                    #pragma unroll
                    for (int j = 0; j < 8; j++) acc[j] += hkk * (float)w[j];
                }
                #pragma unroll
                for (int off = 8; off <= 32; off <<= 1) {
                    #pragma unroll
                    for (int j = 0; j < 8; j++) acc[j] += __shfl_xor(acc[j], off);
                }
                if (ksq == 0) {
                    if (cbq < DD) {
                        #pragma unroll
                        for (int j = 0; j < 8; j++) qv[cbq + j] = acc[j] + c_qkvb[l][cbq + j];
                    } else if (cbq < 2 * DD) {
                        f16x8 kv;
                        #pragma unroll
                        for (int j = 0; j < 8; j++) kv[j] = (f16)(acc[j] + c_qkvb[l][cbq + j]);
                        *(f16x8*)(Krow + (cbq - DD)) = kv;
                    } else {
                        f16x8 vv;
                        #pragma unroll
                        for (int j = 0; j < 8; j++) vv[j] = (f16)(acc[j] + c_qkvb[l][cbq + j]);
                        *(f16x8*)(Vrow + (cbq - 2 * DD)) = vv;
                    }
                }
            }
            __syncthreads();

            // ===== Phase B: attn (waves 4..7), K/V in-phase (rows <= i);
            // ===== all threads prefetch wp4 for phase C                =====
            {
                const f16* W = Wp + (size_t)l * DD * DD + cb2;
                #pragma unroll
                for (int k = 0; k < 4; k++) wp4[k] = *(const f16x8*)(W + (size_t)(ks2 * 4 + k) * DD);
            }
            if (wid >= 4) {
                const int j0 = (lane < i) ? lane : i;            // min(lane, i)
                const int j1 = (lane + 64 < i) ? (lane + 64) : i;
                const f16* K0p = Kl + (size_t)j0 * DD + hh * DHD;
                const f16* K1p = Kl + (size_t)j1 * DD + hh * DHD;
                f16x8 kr0[4], kr1[4];
                #pragma unroll
                for (int g = 0; g < 4; g++) {
                    kr0[g] = *(const f16x8*)(K0p + g * 8);
                    kr1[g] = *(const f16x8*)(K1p + g * 8);
                }
                f16x8 vreg[8];
                const f16* Vp = Vl + hh * DHD + vcg * 8;
                #pragma unroll
                for (int t = 0; t < 8; t++) {
                    int row = vjs * 8 + t; row = (row < i) ? row : i;   // min(row, i)
                    vreg[t] = *(const f16x8*)(Vp + (size_t)row * DD);
                }
                const bool ok0 = (lane <= i), ok1 = (lane + 64 <= i);
                float d0 = 0.f, d1 = 0.f;
                #pragma unroll
                for (int g = 0; g < 4; g++) {
                    f16x8 ka = kr0[g], kb2 = kr1[g];
                    float4 qa = *(const float4*)&qv[hh * DHD + g * 8];
                    float4 qb = *(const float4*)&qv[hh * DHD + g * 8 + 4];
                    d0 += qa.x*(float)ka[0] + qa.y*(float)ka[1] + qa.z*(float)ka[2] + qa.w*(float)ka[3]
                        + qb.x*(float)ka[4] + qb.y*(float)ka[5] + qb.z*(float)ka[6] + qb.w*(float)ka[7];
                    d1 += qa.x*(float)kb2[0] + qa.y*(float)kb2[1] + qa.z*(float)kb2[2] + qa.w*(float)kb2[3]
                        + qb.x*(float)kb2[4] + qb.y*(float)kb2[5] + qb.z*(float)kb2[6] + qb.w*(float)kb2[7];
                }
                const float sscale = 0.17677669529663687f;
                float s0 = ok0 ? d0 * sscale : -1e30f;
                float s1 = ok1 ? d1 * sscale : -1e30f;
                float mx = wave_xor_max(fmaxf(s0, s1));
                float e0 = ok0 ? expf(s0 - mx) : 0.f;
                float e1 = ok1 ? expf(s1 - mx) : 0.f;
                float inv = 1.f / wave_xor_sum(e0 + e1);
                sc[hh][lane]      = e0 * inv;      // rows > i get exactly 0
                sc[hh][lane + 64] = e1 * inv;
                __builtin_amdgcn_wave_barrier();   // compiler fence: sc write -> read (same wave)
                // AV (clamped rows have p == 0)
                const int ja = vjs * 8;
                float4 pa = *(const float4*)&sc[hh][ja];
                float4 pb = *(const float4*)&sc[hh][ja + 4];
                float pv[8] = {pa.x, pa.y, pa.z, pa.w, pb.x, pb.y, pb.z, pb.w};
                float a[8] = {0.f,0.f,0.f,0.f,0.f,0.f,0.f,0.f};
                #pragma unroll
                for (int t = 0; t < 8; t++) {
                    f16x8 vv = vreg[t];
                    float p = pv[t];
                    #pragma unroll
                    for (int u = 0; u < 8; u++) a[u] += p * (float)vv[u];
                }
                #pragma unroll
                for (int off = 4; off <= 32; off <<= 1) {
                    #pragma unroll
                    for (int u = 0; u < 8; u++) a[u] += __shfl_xor(a[u], off);
                }
                if (vjs == 0) {
                    #pragma unroll
                    for (int u = 0; u < 8; u++) o[hh * DHD + vcg * 8 + u] = a[u];
                }
            }
            __syncthreads();

            // ==== Phase C: proj + residual; prefetch wf after FMA loop ====
            {
                float4 ov = *(const float4*)&o[ks2 * 4];
                float oo[4] = {ov.x, ov.y, ov.z, ov.w};
                float acc[8] = {0.f,0.f,0.f,0.f,0.f,0.f,0.f,0.f};
                #pragma unroll
                for (int k = 0; k < 4; k++) {
                    f16x8 w = wp4[k];
                    float ok_ = oo[k];
                    #pragma unroll
                    for (int j = 0; j < 8; j++) acc[j] += ok_ * (float)w[j];
                }
                // wp4 dead -> prefetch wf for phase D (overlaps reduce tail)
                {
                    const f16* W = Wf + (size_t)l * DD * D4 + cbq;
                    #pragma unroll
                    for (int k = 0; k < 16; k++) wf[k] = *(const f16x8*)(W + (size_t)(k0q + k) * D4);
                }
                #pragma unroll
                for (int off = 2; off <= 32; off <<= 1) {
                    #pragma unroll
                    for (int j = 0; j < 8; j++) acc[j] += __shfl_xor(acc[j], off);
                }
                if (ks2 == 0) {
                    #pragma unroll
                    for (int j = 0; j < 8; j++) x[cb2 + j] += acc[j] + c_projb[l][cb2 + j];
                }
            }
            __syncthreads();

            // == Phase D: LN2(inline) + fc + gelu; prefetch wf2 after FMA ==
            {
                float v0 = x[lane], v1 = x[lane + 64];
                float sm = wave_xor_sum(v0 + v1);
                float sq = wave_xor_sum(v0 * v0 + v1 * v1);
                float m  = sm * (1.f / DD);
                float rs = rsqrtf(sq * (1.f / DD) - m * m + 1e-5f);
                float hk[16];
                #pragma unroll
                for (int t = 0; t < 4; t++) {
                    float4 xx = *(const float4*)&x[k0q + 4 * t];
                    float4 ww = *(const float4*)&c_ln2w[l][k0q + 4 * t];
                    float4 bb = *(const float4*)&c_ln2b[l][k0q + 4 * t];
                    hk[4 * t + 0] = (xx.x - m) * rs * ww.x + bb.x;
                    hk[4 * t + 1] = (xx.y - m) * rs * ww.y + bb.y;
                    hk[4 * t + 2] = (xx.z - m) * rs * ww.z + bb.z;
                    hk[4 * t + 3] = (xx.w - m) * rs * ww.w + bb.w;
                }
                float acc[8] = {0.f,0.f,0.f,0.f,0.f,0.f,0.f,0.f};
                #pragma unroll
                for (int k = 0; k < 16; k++) {
                    f16x8 w = wf[k];
                    float hkk = hk[k];
                    #pragma unroll
                    for (int j = 0; j < 8; j++) acc[j] += hkk * (float)w[j];
                }
                // wf dead -> prefetch wf2 for phase E
                {
                    const f16* W = Wf2 + (size_t)l * D4 * DD + cb2;
                    #pragma unroll
                    for (int k = 0; k < 16; k++) wf2[k] = *(const f16x8*)(W + (size_t)(ks2 * 16 + k) * DD);
                }
                #pragma unroll
                for (int off = 8; off <= 32; off <<= 1) {
                    #pragma unroll
                    for (int j = 0; j < 8; j++) acc[j] += __shfl_xor(acc[j], off);
                }
                if (ksq == 0) {
                    #pragma unroll
                    for (int j = 0; j < 8; j++) hmid[cbq + j] = gelu_tanh(acc[j] + c_fcb[l][cbq + j]);
                }
            }
            __syncthreads();

            // == Phase E: fc2 + residual; prefetch wq(next layer) after FMA ==
            {
                float mk[16];
                #pragma unroll
                for (int t = 0; t < 4; t++) {
                    float4 mm = *(const float4*)&hmid[ks2 * 16 + 4 * t];
                    mk[4 * t + 0] = mm.x; mk[4 * t + 1] = mm.y;
                    mk[4 * t + 2] = mm.z; mk[4 * t + 3] = mm.w;
                }
                float acc[8] = {0.f,0.f,0.f,0.f,0.f,0.f,0.f,0.f};
                #pragma unroll
                for (int k = 0; k < 16; k++) {
                    f16x8 w = wf2[k];
                    float mkk = mk[k];
                    #pragma unroll
                    for (int j = 0; j < 8; j++) acc[j] += mkk * (float)w[j];
                }
                // wf2 dead -> prefetch wq for next layer's phase A
                {
                    const int ln = (l + 1 == NL) ? 0 : (l + 1);
                    if (wid < 6) {
                        const f16* W = Wq + (size_t)ln * DD * D3 + cbq;
                        #pragma unroll
                        for (int k = 0; k < 16; k++) wq[k] = *(const f16x8*)(W + (size_t)(k0q + k) * D3);
                    }
                }
                #pragma unroll
                for (int off = 2; off <= 32; off <<= 1) {
                    #pragma unroll
                    for (int j = 0; j < 8; j++) acc[j] += __shfl_xor(acc[j], off);
                }
                if (ks2 == 0) {
                    #pragma unroll
                    for (int j = 0; j < 8; j++) x[cb2 + j] += acc[j] + c_fc2b[l][cb2 + j];
                }
            }
            __syncthreads();
        } // layers

        // ==== head + state update + x-init for step i+1 (wave 0 only) ====
        if (wid == 0) {
            float v0 = x[lane], v1 = x[lane + 64];
            float sm = wave_xor_sum(v0 + v1);
            float sq = wave_xor_sum(v0 * v0 + v1 * v1);
            float m  = sm * (1.f / DD);
            float rs = rsqrtf(sq * (1.f / DD) - m * m + 1e-5f);
            float h0 = (v0 - m) * rs * c_lnfw[lane]      + c_lnfb[lane];
            float h1 = (v1 - m) * rs * c_lnfw[lane + 64] + c_lnfb[lane + 64];
            float v  = wave_xor_sum(h0 * c_headw[lane] + h1 * c_headw[lane + 64]);
            float un = v + hb;
            float s  = s_reg;
            if (lane == 0) Y[b * TH + i] = s;
            float sn = s + (-p0 * s + p1 * tanhf(un));
            s_reg = sn;
            float e = r_next - sn;
            x[lane]      = e * c_wte0[lane]      + un * c_wte1[lane]      + c_wteb[lane]      + wpe_a;
            x[lane + 64] = e * c_wte0[lane + 64] + un * c_wte1[lane + 64] + c_wteb[lane + 64] + wpe_b;
        }
        __syncthreads();
    } // steps
}

extern "C" void kernel_launch(void* const* d_in, const int* in_sizes, int n_in,
                              void* d_out, int out_size, void* d_ws, size_t ws_size,
                              hipStream_t stream) {
    const float* data   = (const float*)d_in[0];
    const float* r      = (const float*)d_in[1];
    const float* wte_w  = (const float*)d_in[2];
    const float* wte_b  = (const float*)d_in[3];
    const float* wpe    = (const float*)d_in[4];
    const float* ln1_w  = (const float*)d_in[5];
    const float* ln1_b  = (const float*)d_in[6];
    const float* ln2_w  = (const float*)d_in[7];
    const float* ln2_b  = (const float*)d_in[8];
    const float* qkv_w  = (const float*)d_in[9];
    const float* qkv_b  = (const float*)d_in[10];
    const float* proj_w = (const float*)d_in[11];
    const float* proj_b = (const float*)d_in[12];
    const float* fc_w   = (const float*)d_in[13];
    const float* fc_b   = (const float*)d_in[14];
    const float* fc2_w  = (const float*)d_in[15];
    const float* fc2_b  = (const float*)d_in[16];
    const float* lnf_w  = (const float*)d_in[17];
    const float* lnf_b  = (const float*)d_in[18];
    const float* head_w = (const float*)d_in[19];
    const float* head_b = (const float*)d_in[20];

    f16* wsp = (f16*)d_ws;
    f16* Wq  = wsp;
    f16* Wp  = Wq  + NL * DD * D3;
    f16* Wf  = Wp  + NL * DD * DD;
    f16* Wf2 = Wf  + NL * DD * D4;
    f16* Kc  = Wf2 + NL * D4 * DD;
    f16* Vc  = Kc  + (size_t)NB * NL * TCAP * DD;

    const int n_w = NL * DD * D3 + NL * DD * DD + NL * DD * D4 + NL * D4 * DD;
    prep_kernel<<<(n_w + 255) / 256, 256, 0, stream>>>(qkv_w, proj_w, fc_w, fc2_w, Wq);

    gpt_loop<<<NB, 512, 0, stream>>>(
        data, r, wte_w, wte_b, wpe, ln1_w, ln1_b, ln2_w, ln2_b,
        qkv_b, proj_b, fc_b, fc2_b, lnf_w, lnf_b, head_w, head_b,
        Wq, Wp, Wf, Wf2, Kc, Vc, (float*)d_out);
}